// Round 2
// baseline (117.671 us; speedup 1.0000x reference)
//
#include <hip/hip_runtime.h>
#include <hip/hip_bf16.h>

#define NN 8192
#define DD 64

typedef __attribute__((ext_vector_type(8))) short short8;
typedef __attribute__((ext_vector_type(4))) float f32x4;

__device__ inline ushort f2bf(float f) {
    union { float f; unsigned u; } v; v.f = f;
    unsigned u = v.u;
    unsigned r = (u + 0x7FFFu + ((u >> 16) & 1u)) >> 16;
    return (ushort)r;
}

// Kernel 1: src[i] = h[i,:]·a1 , dst[i] = h[i,:]·a2   (wave per row)
__global__ __launch_bounds__(256) void srcdst_kernel(
    const float* __restrict__ h, const float* __restrict__ a,
    float* __restrict__ src, float* __restrict__ dst)
{
    int row  = blockIdx.x * 4 + (threadIdx.x >> 6);
    int lane = threadIdx.x & 63;
    float v = h[(size_t)row * DD + lane];
    float s = v * a[lane];
    float t = v * a[DD + lane];
    #pragma unroll
    for (int m = 32; m; m >>= 1) {
        s += __shfl_xor(s, m);
        t += __shfl_xor(t, m);
    }
    if (lane == 0) { src[row] = s; dst[row] = t; }
}

// Kernel 2: pack h (fp32) into bf16 MFMA-B-fragment order.
// HB[c][t][l][e] = bf16( h[ c*32 + (l>>4)*8 + e ][ t*16 + (l&15) ] )
__global__ __launch_bounds__(256) void pack_kernel(
    const float* __restrict__ h, ushort* __restrict__ HB)
{
    int tid = blockIdx.x * 256 + threadIdx.x;   // 0 .. N*DD-1
    int e = tid & 7;
    int l = (tid >> 3) & 63;
    int t = (tid >> 9) & 3;
    int c = tid >> 11;
    int row = c * 32 + ((l >> 4) << 3) + e;
    int col = t * 16 + (l & 15);
    HB[tid] = f2bf(h[(size_t)row * DD + col]);
}

// Kernel 3: flash-style masked softmax + PV via bf16 MFMA, with a runtime
// MFMA-layout self-probe so the C-write is correct under ANY bijective
// fragment lane mapping.
__global__ __launch_bounds__(256) void gat_main(
    const int*   __restrict__ adj,
    const float* __restrict__ src,
    const float* __restrict__ dst,
    const ushort* __restrict__ HB,
    float* __restrict__ out)
{
    int tid  = threadIdx.x;
    int w    = tid >> 6;
    int lane = tid & 63;
    int r    = lane & 15;   // our "row label" (P-row / src / adj row)
    int g    = lane >> 4;
    int i0   = blockIdx.x * 16;

    // ---- layout self-probe ----
    // probe1: A holds row-labels (constant per lane across k), B uniform 1/32.
    //   D[m][n] = label(m)  -> each acc element learns its TRUE row label.
    // probe2: A uniform 1/32, B holds col-labels.
    //   D[m][n] = label(n)  -> each acc element learns its TRUE col label.
    // Exact in bf16/f32: labels 0..15 and 1/32 are exact; sum of 32 * (r/32) = r.
    short8 lab, uni;
    {
        ushort lv = f2bf((float)r);
        ushort uv = f2bf(1.0f / 32.0f);
        #pragma unroll
        for (int e = 0; e < 8; ++e) { lab[e] = (short)lv; uni[e] = (short)uv; }
    }
    f32x4 zf = {};
    f32x4 t_row = __builtin_amdgcn_mfma_f32_16x16x32_bf16(lab, uni, zf, 0, 0, 0);
    f32x4 t_col = __builtin_amdgcn_mfma_f32_16x16x32_bf16(uni, lab, zf, 0, 0, 0);
    int rowlab[4], collab[4];
    #pragma unroll
    for (int q = 0; q < 4; ++q) {
        rowlab[q] = (int)(t_row[q] + 0.5f);
        collab[q] = (int)(t_col[q] + 0.5f);
    }

    float srcv = src[i0 + r];
    f32x4 acc[4] = {};
    float lsum = 0.f;

    const int jbase = w * (NN / 4);
    const int* adjrow = adj + (size_t)(i0 + r) * NN;

    for (int c = 0; c < (NN / 4) / 32; ++c) {
        int j0 = jbase + c * 32;
        int gc = j0 >> 5;                       // global 32-chunk index
        const int jg = j0 + g * 8;
        int4   a0 = *reinterpret_cast<const int4*>(adjrow + jg);
        int4   a1 = *reinterpret_cast<const int4*>(adjrow + jg + 4);
        float4 d0 = *reinterpret_cast<const float4*>(dst + jg);
        float4 d1 = *reinterpret_cast<const float4*>(dst + jg + 4);
        int   am[8] = {a0.x, a0.y, a0.z, a0.w, a1.x, a1.y, a1.z, a1.w};
        float dv[8] = {d0.x, d0.y, d0.z, d0.w, d1.x, d1.y, d1.z, d1.w};
        short8 af;
        #pragma unroll
        for (int e = 0; e < 8; ++e) {
            float ev = srcv + dv[e];
            ev = ev > 0.f ? ev : 0.01f * ev;     // leaky relu
            float pe = (am[e] > 0) ? __expf(ev) : 0.f;
            lsum += pe;
            af[e] = (short)f2bf(pe);
        }
        const ushort* hb = HB + (size_t)gc * 2048 + lane * 8;
        #pragma unroll
        for (int t = 0; t < 4; ++t) {
            short8 bf = *reinterpret_cast<const short8*>(hb + t * 512);
            acc[t] = __builtin_amdgcn_mfma_f32_16x16x32_bf16(af, bf, acc[t], 0, 0, 0);
        }
    }

    // denominator: sum l across the 4 k-groups (lanes r, r+16, r+32, r+48)
    lsum += __shfl_xor(lsum, 16);
    lsum += __shfl_xor(lsum, 32);

    __shared__ float o_sh[4][16][64];
    __shared__ float l_sh[4][16];
    // scatter acc by the MEASURED (row,col) labels -> o_sh is in true coords
    #pragma unroll
    for (int t = 0; t < 4; ++t)
        #pragma unroll
        for (int q = 0; q < 4; ++q)
            o_sh[w][rowlab[q]][t * 16 + collab[q]] = acc[t][q];
    if (g == 0) l_sh[w][r] = lsum;
    __syncthreads();

    for (int it = tid; it < 16 * 64; it += 256) {
        int row = it >> 6, d = it & 63;
        float o  = o_sh[0][row][d] + o_sh[1][row][d] + o_sh[2][row][d] + o_sh[3][row][d];
        float lt = l_sh[0][row] + l_sh[1][row] + l_sh[2][row] + l_sh[3][row];
        out[(size_t)(i0 + row) * DD + d] = o / lt;
    }
}

extern "C" void kernel_launch(void* const* d_in, const int* in_sizes, int n_in,
                              void* d_out, int out_size, void* d_ws, size_t ws_size,
                              hipStream_t stream) {
    const float* h   = (const float*)d_in[0];
    const int*   adj = (const int*)d_in[1];
    const float* a   = (const float*)d_in[2];
    float* out = (float*)d_out;

    float*  src = (float*)d_ws;
    float*  dst = src + NN;
    ushort* HB  = (ushort*)((char*)d_ws + 65536);   // 1 MB region

    srcdst_kernel<<<NN / 4, 256, 0, stream>>>(h, a, src, dst);
    pack_kernel<<<(NN * DD) / 256, 256, 0, stream>>>(h, HB);
    gat_main<<<NN / 16, 256, 0, stream>>>(adj, src, dst, HB, out);
}

// Round 3
// 81.339 us; speedup vs baseline: 1.4467x; 1.4467x over previous
//
#include <hip/hip_runtime.h>
#include <hip/hip_bf16.h>

#define NN 8192
#define DD 64
#define SPLIT 4   // j-range splits per 16-row group

typedef __attribute__((ext_vector_type(8))) short short8;
typedef __attribute__((ext_vector_type(4))) float f32x4;

__device__ inline ushort f2bf(float f) {
    union { float f; unsigned u; } v; v.f = f;
    unsigned u = v.u;
    unsigned r = (u + 0x7FFFu + ((u >> 16) & 1u)) >> 16;
    return (ushort)r;
}

// Kernel 1: src[i] = h[i,:]·a1 , dst[i] = h[i,:]·a2   (wave per row)
__global__ __launch_bounds__(256) void srcdst_kernel(
    const float* __restrict__ h, const float* __restrict__ a,
    float* __restrict__ src, float* __restrict__ dst)
{
    int row  = blockIdx.x * 4 + (threadIdx.x >> 6);
    int lane = threadIdx.x & 63;
    float v = h[(size_t)row * DD + lane];
    float s = v * a[lane];
    float t = v * a[DD + lane];
    #pragma unroll
    for (int m = 32; m; m >>= 1) {
        s += __shfl_xor(s, m);
        t += __shfl_xor(t, m);
    }
    if (lane == 0) { src[row] = s; dst[row] = t; }
}

// Kernel 2: pack h (fp32) into bf16 MFMA-B-fragment order.
// HB[c][t][l][e] = bf16( h[ c*32 + (l>>4)*8 + e ][ t*16 + (l&15) ] )
__global__ __launch_bounds__(256) void pack_kernel(
    const float* __restrict__ h, ushort* __restrict__ HB)
{
    int tid = blockIdx.x * 256 + threadIdx.x;   // 0 .. N*DD-1
    int e = tid & 7;
    int l = (tid >> 3) & 63;
    int t = (tid >> 9) & 3;
    int c = tid >> 11;
    int row = c * 32 + ((l >> 4) << 3) + e;
    int col = t * 16 + (l & 15);
    HB[tid] = f2bf(h[(size_t)row * DD + col]);
}

// Kernel 3: flash-style masked softmax + PV via bf16 MFMA.
// Grid = (NN/16)*SPLIT blocks. Block (ig,sp): rows [ig*16,ig*16+16),
// j in [sp*(NN/SPLIT), ...). 4 waves split that j-range again by 4.
// Writes fp32 partial numerator/denominator to workspace.
__global__ __launch_bounds__(256) void gat_main(
    const int*   __restrict__ adj,
    const float* __restrict__ src,
    const float* __restrict__ dst,
    const ushort* __restrict__ HB,
    float* __restrict__ po,   // [NN/16][SPLIT][16][64]
    float* __restrict__ pl)   // [NN/16][SPLIT][16]
{
    int tid  = threadIdx.x;
    int w    = tid >> 6;
    int lane = tid & 63;
    int r    = lane & 15;   // row label (P-row / src / adj row)
    int g    = lane >> 4;
    int ig   = blockIdx.x / SPLIT;
    int sp   = blockIdx.x % SPLIT;
    int i0   = ig * 16;

    // ---- MFMA layout self-probe (exact; makes C-write mapping-agnostic) ----
    short8 lab, uni;
    {
        ushort lv = f2bf((float)r);
        ushort uv = f2bf(1.0f / 32.0f);
        #pragma unroll
        for (int e = 0; e < 8; ++e) { lab[e] = (short)lv; uni[e] = (short)uv; }
    }
    f32x4 zf = {};
    f32x4 t_row = __builtin_amdgcn_mfma_f32_16x16x32_bf16(lab, uni, zf, 0, 0, 0);
    f32x4 t_col = __builtin_amdgcn_mfma_f32_16x16x32_bf16(uni, lab, zf, 0, 0, 0);
    int rowlab[4], collab[4];
    #pragma unroll
    for (int q = 0; q < 4; ++q) {
        rowlab[q] = (int)(t_row[q] + 0.5f);
        collab[q] = (int)(t_col[q] + 0.5f);
    }

    float srcv = src[i0 + r];
    f32x4 acc[4] = {};
    float lsum = 0.f;

    const int jbase = sp * (NN / SPLIT) + w * (NN / SPLIT / 4);
    const int* adjrow = adj + (size_t)(i0 + r) * NN;

    for (int c = 0; c < (NN / SPLIT / 4) / 32; ++c) {
        int j0 = jbase + c * 32;
        int gc = j0 >> 5;                       // global 32-chunk index
        const int jg = j0 + g * 8;
        int4   a0 = *reinterpret_cast<const int4*>(adjrow + jg);
        int4   a1 = *reinterpret_cast<const int4*>(adjrow + jg + 4);
        float4 d0 = *reinterpret_cast<const float4*>(dst + jg);
        float4 d1 = *reinterpret_cast<const float4*>(dst + jg + 4);
        int   am[8] = {a0.x, a0.y, a0.z, a0.w, a1.x, a1.y, a1.z, a1.w};
        float dv[8] = {d0.x, d0.y, d0.z, d0.w, d1.x, d1.y, d1.z, d1.w};
        short8 af;
        #pragma unroll
        for (int e = 0; e < 8; ++e) {
            float ev = srcv + dv[e];
            ev = fmaxf(ev, 0.01f * ev);          // leaky relu (slope<1)
            float pe = (am[e] > 0) ? __expf(ev) : 0.f;
            lsum += pe;
            af[e] = (short)f2bf(pe);
        }
        const ushort* hb = HB + (size_t)gc * 2048 + lane * 8;
        #pragma unroll
        for (int t = 0; t < 4; ++t) {
            short8 bf = *reinterpret_cast<const short8*>(hb + t * 512);
            acc[t] = __builtin_amdgcn_mfma_f32_16x16x32_bf16(af, bf, acc[t], 0, 0, 0);
        }
    }

    // denominator: sum across the 4 k-groups (lanes r, r+16, r+32, r+48)
    lsum += __shfl_xor(lsum, 16);
    lsum += __shfl_xor(lsum, 32);

    __shared__ float o_sh[4][16][64];
    __shared__ float l_sh[4][16];
    #pragma unroll
    for (int t = 0; t < 4; ++t)
        #pragma unroll
        for (int q = 0; q < 4; ++q)
            o_sh[w][rowlab[q]][t * 16 + collab[q]] = acc[t][q];
    if (g == 0) l_sh[w][r] = lsum;
    __syncthreads();

    float* pob = po + ((size_t)blockIdx.x) * 16 * 64;
    for (int it = tid; it < 16 * 64; it += 256) {
        int row = it >> 6, d = it & 63;
        pob[it] = o_sh[0][row][d] + o_sh[1][row][d] + o_sh[2][row][d] + o_sh[3][row][d];
    }
    if (tid < 16)
        pl[(size_t)blockIdx.x * 16 + tid] =
            l_sh[0][tid] + l_sh[1][tid] + l_sh[2][tid] + l_sh[3][tid];
}

// Kernel 4: combine SPLIT partials, divide, write out.
__global__ __launch_bounds__(256) void reduce_kernel(
    const float* __restrict__ po, const float* __restrict__ pl,
    float* __restrict__ out)
{
    int idx = blockIdx.x * 256 + threadIdx.x;   // 0 .. NN*DD-1
    int row = idx >> 6;
    int d   = idx & 63;
    int ig  = row >> 4;
    int r   = row & 15;
    float o = 0.f, l = 0.f;
    #pragma unroll
    for (int sp = 0; sp < SPLIT; ++sp) {
        int b = ig * SPLIT + sp;
        o += po[((size_t)b * 16 + r) * 64 + d];
        l += pl[(size_t)b * 16 + r];
    }
    out[idx] = o / l;
}

extern "C" void kernel_launch(void* const* d_in, const int* in_sizes, int n_in,
                              void* d_out, int out_size, void* d_ws, size_t ws_size,
                              hipStream_t stream) {
    const float* h   = (const float*)d_in[0];
    const int*   adj = (const int*)d_in[1];
    const float* a   = (const float*)d_in[2];
    float* out = (float*)d_out;

    char* ws = (char*)d_ws;
    float*  src = (float*)ws;                       // 32 KB
    float*  dst = src + NN;                         // 32 KB
    ushort* HB  = (ushort*)(ws + (1u << 16));       // 1 MB
    float*  po  = (float*)(ws + (2u << 20));        // (NN/16)*SPLIT*16*64*4 = 8 MB
    float*  pl  = (float*)(ws + (12u << 20));       // 128 KB

    srcdst_kernel<<<NN / 4, 256, 0, stream>>>(h, a, src, dst);
    pack_kernel<<<(NN * DD) / 256, 256, 0, stream>>>(h, HB);
    gat_main<<<(NN / 16) * SPLIT, 256, 0, stream>>>(adj, src, dst, HB, po, pl);
    reduce_kernel<<<(NN * DD) / 256, 256, 0, stream>>>(po, pl, out);
}